// Round 9
// baseline (1379.625 us; speedup 1.0000x reference)
//
#include <hip/hip_runtime.h>
#include <math.h>

#define TPB 256
#define LRATE 0.005f

// Bucketed CSR build parameters
#define LOG_NPB 11
#define NPB (1 << LOG_NPB)   // 2048 nodes per bucket
#define CAP 24576            // max edges/bucket (mean 20480 @ avg deg 10; +28 sigma)
#define CHUNK 4096           // edges per partition block
#define CPT (CHUNK / TPB)    // 16 edges per thread

#define GATHER_BLOCKS 2048   // 8 blocks/CU co-resident (LDS 139KB, VGPR<=64)

// clang vector type for nontemporal builtins (HIP float4 is a class -> rejected)
typedef float vf4 __attribute__((ext_vector_type(4)));

// ---------------------------------------------------------------------------
// fp8 e4m3fn helpers (OCP). hp values |v| ~ O(10) << 448.
#if __has_builtin(__builtin_amdgcn_cvt_f32_fp8) && __has_builtin(__builtin_amdgcn_cvt_pk_fp8_f32)
__device__ __forceinline__ float fp8_dec(unsigned char v) {
    return __builtin_amdgcn_cvt_f32_fp8((int)v, 0);
}
__device__ __forceinline__ unsigned fp8_pk4(float a, float b, float c, float d) {
    int w = __builtin_amdgcn_cvt_pk_fp8_f32(a, b, 0, false);
    w = __builtin_amdgcn_cvt_pk_fp8_f32(c, d, w, true);
    return (unsigned)w;
}
#else
__device__ __forceinline__ unsigned char fp8_enc1(float f) {
    unsigned u = __float_as_uint(f);
    unsigned s = (u >> 24) & 0x80u;
    u &= 0x7FFFFFFFu;
    if (u >= 0x43E00000u) return (unsigned char)(s | 0x7E);
    if (u < 0x3C800000u) {
        float a = __uint_as_float(u);
        int m = (int)rintf(a * 512.f);
        return (unsigned char)(s | (unsigned)m);
    }
    unsigned mant = u & 0x7FFFFFu;
    unsigned rest = mant & 0xFFFFFu;
    unsigned keep = u >> 20;
    keep += (rest > 0x80000u || (rest == 0x80000u && (keep & 1u))) ? 1u : 0u;
    int eb = (int)(keep >> 3) - 127 + 7;
    return (unsigned char)(s | (unsigned)((eb << 3) | (int)(keep & 7u)));
}
__device__ __forceinline__ float fp8_dec(unsigned char v) {
    unsigned s = ((unsigned)(v & 0x80u)) << 24;
    unsigned e = (v >> 3) & 0xFu;
    unsigned m = v & 7u;
    if (e == 0) {
        float r = (float)m * 0.001953125f;
        return (v & 0x80u) ? -r : r;
    }
    return __uint_as_float(s | ((e + 120u) << 23) | (m << 20));
}
__device__ __forceinline__ unsigned fp8_pk4(float a, float b, float c, float d) {
    return (unsigned)fp8_enc1(a) | ((unsigned)fp8_enc1(b) << 8) |
           ((unsigned)fp8_enc1(c) << 16) | ((unsigned)fp8_enc1(d) << 24);
}
#endif

// ---------------------------------------------------------------------------
// K_PART: partition edges into per-bucket record arrays (bucket = dst >> 11).
__global__ __launch_bounds__(TPB) void k_partition(const int* __restrict__ src,
                                                   const int* __restrict__ dst,
                                                   int* __restrict__ bcur,
                                                   int* __restrict__ grec,
                                                   int E, int nbuck) {
    __shared__ int hist[TPB];
    __shared__ int sc[TPB];
    __shared__ int lstart[TPB];
    __shared__ int lcur[TPB];
    __shared__ int gbase[TPB];
    __shared__ int lbuf[CHUNK];
    __shared__ unsigned char bbuf[CHUNK];

    int t = threadIdx.x;
    int chunkBase = blockIdx.x * CHUNK;
    hist[t] = 0;
    __syncthreads();

    int myb[CPT], myrec[CPT];
#pragma unroll
    for (int k = 0; k < CPT; k++) {
        int e = chunkBase + k * TPB + t;
        if (e < E) {
            int d = dst[e];
            int s = src[e];
            int b = d >> LOG_NPB;
            myb[k] = b;
            myrec[k] = (s << LOG_NPB) | (d & (NPB - 1));
            atomicAdd(&hist[b], 1);
        } else myb[k] = -1;
    }
    __syncthreads();

    int c = hist[t];
    sc[t] = c;
    __syncthreads();
#pragma unroll
    for (int off = 1; off < TPB; off <<= 1) {
        int add = (t >= off) ? sc[t - off] : 0;
        __syncthreads();
        sc[t] += add;
        __syncthreads();
    }
    int excl = sc[t] - c;
    lstart[t] = excl;
    lcur[t] = excl;
    if (t < nbuck && c > 0) gbase[t] = atomicAdd(&bcur[t * 16], c);
    __syncthreads();

#pragma unroll
    for (int k = 0; k < CPT; k++) {
        if (myb[k] >= 0) {
            int p = atomicAdd(&lcur[myb[k]], 1);
            lbuf[p] = myrec[k];
            bbuf[p] = (unsigned char)myb[k];
        }
    }
    __syncthreads();

    int total = E - chunkBase; if (total > CHUNK) total = CHUNK;
    for (int p = t; p < total; p += TPB) {
        int b = bbuf[p];
        int pos = gbase[b] + (p - lstart[b]);
        if (pos < CAP) grec[(size_t)b * CAP + pos] = lbuf[p];
    }
}

// K_BUILD: one block per bucket — LDS histograms (total + low-src-half), scan,
// split adjacency scatter (low srcs first), coalesced writeout.
// Emits rowptr/rowmid/rowend/dinv. LDS ~137 KB -> 1 block/CU.
__global__ __launch_bounds__(TPB) void k_build(const int* __restrict__ bcur,
                                               const int* __restrict__ grec,
                                               int* __restrict__ adj,
                                               int* __restrict__ rowptr,
                                               int* __restrict__ rowmid,
                                               int* __restrict__ rowend,
                                               float* __restrict__ dinv,
                                               int N, int half) {
    __shared__ int deg[NPB];
    __shared__ int dlo[NPB];
    __shared__ int lrow[NPB];
    __shared__ int clo[NPB];
    __shared__ int chi[NPB];
    __shared__ int sscan[TPB];
    __shared__ int adjL[CAP];

    int t = threadIdx.x;
    int b = blockIdx.x;
    int cnt = bcur[b * 16]; if (cnt > CAP) cnt = CAP;
    const int nodeBase = b << LOG_NPB;
    const size_t recBase = (size_t)b * CAP;

    for (int i = t; i < NPB; i += TPB) { deg[i] = 0; dlo[i] = 0; }
    __syncthreads();
    for (int i = t; i < cnt; i += TPB) {
        int r = grec[recBase + i];
        int node = r & (NPB - 1);
        atomicAdd(&deg[node], 1);
        if ((int)(((unsigned)r) >> LOG_NPB) < half) atomicAdd(&dlo[node], 1);
    }
    __syncthreads();

    int dv[8]; int c8 = 0;
#pragma unroll
    for (int j = 0; j < 8; j++) { dv[j] = deg[t * 8 + j]; c8 += dv[j]; }
    sscan[t] = c8;
    __syncthreads();
#pragma unroll
    for (int off = 1; off < TPB; off <<= 1) {
        int add = (t >= off) ? sscan[t - off] : 0;
        __syncthreads();
        sscan[t] += add;
        __syncthreads();
    }
    int run = sscan[t] - c8;
#pragma unroll
    for (int j = 0; j < 8; j++) { lrow[t * 8 + j] = run; run += dv[j]; }
    __syncthreads();

    for (int i = t; i < NPB; i += TPB) {
        int node = nodeBase + i;
        if (node < N) {
            int rp = (int)recBase + lrow[i];
            rowptr[node] = rp;
            rowmid[node] = rp + dlo[i];
            rowend[node] = rp + deg[i];
            dinv[node] = rsqrtf((float)(deg[i] + 1));
        }
        clo[i] = lrow[i];
        chi[i] = lrow[i] + dlo[i];
    }
    __syncthreads();

    for (int i = t; i < cnt; i += TPB) {
        int r = grec[recBase + i];
        int node = r & (NPB - 1);
        int srcid = (int)(((unsigned)r) >> LOG_NPB);
        int p = (srcid < half) ? atomicAdd(&clo[node], 1) : atomicAdd(&chi[node], 1);
        adjL[p] = srcid;
    }
    __syncthreads();
    for (int i = t; i < cnt; i += TPB) adj[recBase + i] = adjL[i];
}

// ---------------------------------------------------------------------------
// K3: hp = fp8_e4m3( dinv * (x @ W.T) ) — 16B rows. fp32 compute.
__global__ __launch_bounds__(TPB) void k_h(const float* __restrict__ xc,
                                           const float* __restrict__ W,
                                           const float* __restrict__ dinv,
                                           unsigned* __restrict__ hp, int n) {
    __shared__ float sW[256];
    if (threadIdx.x < 256) sW[threadIdx.x] = W[threadIdx.x];
    __syncthreads();
    int i = blockIdx.x * blockDim.x + threadIdx.x;
    int stride = gridDim.x * blockDim.x;
    for (; i < n; i += stride) {
        float x[16];
        const float4* xr = (const float4*)(xc + (size_t)i * 16);
#pragma unroll
        for (int q = 0; q < 4; q++) {
            float4 v = xr[q];
            x[4*q+0] = v.x; x[4*q+1] = v.y; x[4*q+2] = v.z; x[4*q+3] = v.w;
        }
        float di = dinv[i];
        float hv[16];
#pragma unroll
        for (int j = 0; j < 16; j++) {
            float s = 0.f;
#pragma unroll
            for (int k = 0; k < 16; k++) s = fmaf(x[k], sW[j*16 + k], s);
            hv[j] = di * s;
        }
        uint4 w;
        w.x = fp8_pk4(hv[0],  hv[1],  hv[2],  hv[3]);
        w.y = fp8_pk4(hv[4],  hv[5],  hv[6],  hv[7]);
        w.z = fp8_pk4(hv[8],  hv[9],  hv[10], hv[11]);
        w.w = fp8_pk4(hv[12], hv[13], hv[14], hv[15]);
        ((uint4*)hp)[i] = w;
    }
}

// K4 (fused, 2-phase L2-resident gather). Phase 1 gathers low-src edges
// (hp-low 3.8 MB fits one XCD L2), parks partials in LDS; soft grid barrier
// (performance-only, bounded spin, no deadlock possible); phase 2 gathers
// high-src edges + fused ReLU/z/dW/db epilogue. Streams are NT so they
// can't evict the L2-resident hp half.
__global__ __launch_bounds__(TPB, 8) void k_gather(const int* __restrict__ rowptr,
                                                   const int* __restrict__ rowmid,
                                                   const int* __restrict__ rowend,
                                                   const float* __restrict__ dinv,
                                                   const unsigned char* __restrict__ hp,
                                                   const float* __restrict__ b,
                                                   const float* __restrict__ xc,
                                                   float* __restrict__ z,
                                                   float* __restrict__ partial,
                                                   int* __restrict__ barctr,
                                                   const int* __restrict__ adj,
                                                   int nb, int n, int rpb) {
    __shared__ float s[4352];   // phase-1 acc [rpb<=272][16]; later red[256][17]
    int t = threadIdx.x;
    int j = t & 15;
    int grp = t >> 4;
    int rbeg = blockIdx.x * rpb;
    int rend_b = rbeg + rpb; if (rend_b > n) rend_b = n;

    // --- phase 1: self term + low-half gather -> LDS ---
    for (int g = rbeg + grp; g < rend_b; g += 16) {
        int e  = __builtin_nontemporal_load(rowptr + g);
        int em = __builtin_nontemporal_load(rowmid + g);
        float acc = fp8_dec(hp[(size_t)g * 16 + j]);
        for (; e + 3 < em; e += 4) {
            int s0 = __builtin_nontemporal_load(adj + e);
            int s1 = __builtin_nontemporal_load(adj + e + 1);
            int s2 = __builtin_nontemporal_load(adj + e + 2);
            int s3 = __builtin_nontemporal_load(adj + e + 3);
            acc += (fp8_dec(hp[(size_t)s0 * 16 + j]) + fp8_dec(hp[(size_t)s1 * 16 + j]))
                 + (fp8_dec(hp[(size_t)s2 * 16 + j]) + fp8_dec(hp[(size_t)s3 * 16 + j]));
        }
        for (; e < em; e++) {
            int s0 = __builtin_nontemporal_load(adj + e);
            acc += fp8_dec(hp[(size_t)s0 * 16 + j]);
        }
        s[(g - rbeg) * 16 + j] = acc;
    }

    // --- soft grid barrier (performance-only; bounded spin) ---
    __syncthreads();
    if (t == 0) {
        __threadfence();
        atomicAdd(barctr, 1);
        int target = (int)gridDim.x;
        int spins = 0;
        while (__hip_atomic_load(barctr, __ATOMIC_RELAXED, __HIP_MEMORY_SCOPE_AGENT) < target
               && spins < 1500) {
            __builtin_amdgcn_s_sleep(16);
            ++spins;
        }
    }
    __syncthreads();

    // --- phase 2: high-half gather + fused epilogue ---
    float accW[16];
#pragma unroll
    for (int k = 0; k < 16; k++) accW[k] = 0.f;
    float accB = 0.f;
    float bj = b[j];

    for (int g = rbeg + grp; g < rend_b; g += 16) {
        int e  = __builtin_nontemporal_load(rowmid + g);
        int ee = __builtin_nontemporal_load(rowend + g);
        float acc = s[(g - rbeg) * 16 + j];
        for (; e + 3 < ee; e += 4) {
            int s0 = __builtin_nontemporal_load(adj + e);
            int s1 = __builtin_nontemporal_load(adj + e + 1);
            int s2 = __builtin_nontemporal_load(adj + e + 2);
            int s3 = __builtin_nontemporal_load(adj + e + 3);
            acc += (fp8_dec(hp[(size_t)s0 * 16 + j]) + fp8_dec(hp[(size_t)s1 * 16 + j]))
                 + (fp8_dec(hp[(size_t)s2 * 16 + j]) + fp8_dec(hp[(size_t)s3 * 16 + j]));
        }
        for (; e < ee; e++) {
            int s0 = __builtin_nontemporal_load(adj + e);
            acc += fp8_dec(hp[(size_t)s0 * 16 + j]);
        }

        float zj = fmaxf(fmaf(__builtin_nontemporal_load(dinv + g), acc, bj), 0.f);
        __builtin_nontemporal_store(zj, z + (size_t)g * 16 + j);
        float wdj = 4.f * zj * zj;
        accB += wdj;
        const vf4* xrow = (const vf4*)(xc + (size_t)g * 16);
        vf4 x0 = __builtin_nontemporal_load(xrow);
        vf4 x1 = __builtin_nontemporal_load(xrow + 1);
        vf4 x2 = __builtin_nontemporal_load(xrow + 2);
        vf4 x3 = __builtin_nontemporal_load(xrow + 3);
        accW[0]  = fmaf(x0.x, wdj, accW[0]);  accW[1]  = fmaf(x0.y, wdj, accW[1]);
        accW[2]  = fmaf(x0.z, wdj, accW[2]);  accW[3]  = fmaf(x0.w, wdj, accW[3]);
        accW[4]  = fmaf(x1.x, wdj, accW[4]);  accW[5]  = fmaf(x1.y, wdj, accW[5]);
        accW[6]  = fmaf(x1.z, wdj, accW[6]);  accW[7]  = fmaf(x1.w, wdj, accW[7]);
        accW[8]  = fmaf(x2.x, wdj, accW[8]);  accW[9]  = fmaf(x2.y, wdj, accW[9]);
        accW[10] = fmaf(x2.z, wdj, accW[10]); accW[11] = fmaf(x2.w, wdj, accW[11]);
        accW[12] = fmaf(x3.x, wdj, accW[12]); accW[13] = fmaf(x3.y, wdj, accW[13]);
        accW[14] = fmaf(x3.z, wdj, accW[14]); accW[15] = fmaf(x3.w, wdj, accW[15]);
    }

    // --- block reduction (overlay red[256][17] on s after all rows done) ---
    __syncthreads();
#pragma unroll
    for (int k = 0; k < 16; k++) s[t * 17 + k] = accW[k];
    s[t * 17 + 16] = accB;
    __syncthreads();
    int kk = t >> 4;
    int jj = t & 15;
    float sum = 0.f;
#pragma unroll
    for (int g = 0; g < 16; g++) sum += s[(g * 16 + jj) * 17 + kk];
    partial[(size_t)(kk * 16 + jj) * nb + blockIdx.x] = sum;
    if (t < 16) {
        float sb = 0.f;
#pragma unroll
        for (int g = 0; g < 16; g++) sb += s[(g * 16 + t) * 17 + 16];
        partial[(size_t)(256 + t) * nb + blockIdx.x] = sb;
    }
}

// K5b: one 64-lane wave per (layer,elem): coalesced sum over nb partials.
__global__ __launch_bounds__(TPB) void k_reduce(const float* __restrict__ partial,
                                                float* __restrict__ acc,
                                                int nb, int total) {
    int wid = (blockIdx.x * blockDim.x + threadIdx.x) >> 6;
    int lane = threadIdx.x & 63;
    if (wid >= total) return;
    const float* p = partial + (size_t)wid * nb;
    float s = 0.f;
    for (int b = lane; b < nb; b += 64) s += p[b];
#pragma unroll
    for (int off = 32; off > 0; off >>= 1) s += __shfl_down(s, off, 64);
    if (lane == 0) acc[wid] = s;
}

// ---------------------------------------------------------------------------
__device__ __forceinline__ float local_loss_f(float g, int positive) {
    const float t = 0.0f;
    if (positive) {
        if (g > t + 10.f) return 0.f;
        if (g < t - 10.f) return t - g;
        return log1pf(expf(t - g));
    } else {
        if (g > t + 10.f) return t + g;
        if (g < t - 10.f) return 0.f;
        return log1pf(expf(g + t));
    }
}

__global__ void k_final(const float* __restrict__ W1, const float* __restrict__ b1,
                        const float* __restrict__ acc, const int* __restrict__ positive,
                        float* __restrict__ outv) {
    int t = threadIdx.x;
    if (t < 256) {
        int jj = t >> 4, kk = t & 15;   // Wc[jj][kk] -= LR * dW[kk][jj]
        float s = 0.f;
#pragma unroll
        for (int l = 0; l < 3; l++) s += acc[l * 272 + kk * 16 + jj];
        outv[1 + t] = W1[t] - LRATE * s;
    }
    if (t < 16) {
        float s = 0.f;
#pragma unroll
        for (int l = 0; l < 3; l++) s += acc[l * 272 + 256 + t];
        outv[257 + t] = b1[t] - LRATE * s;
    }
    if (t == 0) {
        int pos = positive[0];
        float agg = 0.f;
#pragma unroll
        for (int l = 0; l < 3; l++) {
            float g = 0.f;
#pragma unroll
            for (int jj = 0; jj < 16; jj++) g += acc[l * 272 + 256 + jj];
            g *= (1.0f / 64.0f);
            agg += local_loss_f(g, pos);
        }
        outv[0] = agg;
    }
}

extern "C" void kernel_launch(void* const* d_in, const int* in_sizes, int n_in,
                              void* d_out, int out_size, void* d_ws, size_t ws_size,
                              hipStream_t stream) {
    const float* x  = (const float*)d_in[0];
    const int*   ei = (const int*)d_in[1];
    const float* W1 = (const float*)d_in[2];
    const float* b1 = (const float*)d_in[3];
    const float* W2 = (const float*)d_in[4];
    const float* b2 = (const float*)d_in[5];
    const float* W3 = (const float*)d_in[6];
    const float* b3 = (const float*)d_in[7];
    const int* positive = (const int*)d_in[8];
    float* outv = (float*)d_out;

    const int N = in_sizes[0] / 16;
    const int E = in_sizes[1] / 2;
    const int NB = GATHER_BLOCKS;
    const int nbuck = (N + NPB - 1) >> LOG_NPB;
    const int rpb = (N + NB - 1) / NB;              // 245 <= 272 (LDS bound)

    char* ws = (char*)d_ws;
    size_t off = 0;
    auto carve = [&](size_t bytes) -> void* {
        void* p = ws + off;
        off = (off + bytes + 255) & ~(size_t)255;
        return p;
    };
    int*   bcur   = (int*)  carve((size_t)nbuck * 16 * 4);
    int*   sync   = (int*)  carve(256);                       // barrier counters
    int*   adj    = (int*)  carve((size_t)nbuck * CAP * 4);   // 24 MB
    int*   rowptr = (int*)  carve((size_t)N * 4);
    int*   rowmid = (int*)  carve((size_t)N * 4);
    int*   rowend = (int*)  carve((size_t)N * 4);
    float* dinv   = (float*)carve((size_t)N * 4);
    float* acc    = (float*)carve(3 * 272 * 4);
    float* part   = (float*)carve((size_t)3 * 272 * NB * 4);
    unsigned* hp  = (unsigned*)carve((size_t)N * 16);         // fp8 rows, 8 MB
    float* P1     = (float*)carve((size_t)N * 64);
    float* P2     = (float*)carve((size_t)N * 64);
    int*   grec   = (int*)P2;   // dead after k_build; P2 first written layer 2

    (void)hipMemsetAsync(bcur, 0, (size_t)nbuck * 16 * 4, stream);
    (void)hipMemsetAsync(sync, 0, 256, stream);

    const int* src = ei;
    const int* dst = ei + E;

    int partBlocks = (E + CHUNK - 1) / CHUNK;
    k_partition<<<partBlocks, TPB, 0, stream>>>(src, dst, bcur, grec, E, nbuck);
    k_build<<<nbuck, TPB, 0, stream>>>(bcur, grec, adj, rowptr, rowmid, rowend,
                                       dinv, N, N / 2);

    const float* bss[3] = {b1, b2, b3};
    float* outs[3] = {P1, P2, P1};
    const float* Ws[3] = {W1, W2, W3};

    int nodeBlocks = (N + TPB - 1) / TPB;

    const float* xc = x;
    for (int l = 0; l < 3; l++) {
        k_h<<<nodeBlocks, TPB, 0, stream>>>(xc, Ws[l], dinv, hp, N);
        k_gather<<<NB, TPB, 0, stream>>>(rowptr, rowmid, rowend, dinv,
                                         (const unsigned char*)hp, bss[l],
                                         xc, outs[l],
                                         part + (size_t)l * 272 * NB,
                                         sync + l, adj, NB, N, rpb);
        xc = outs[l];
    }
    int totalElems = 3 * 272;
    k_reduce<<<(totalElems * 64 + TPB - 1) / TPB, TPB, 0, stream>>>(part, acc, NB, totalElems);
    k_final<<<1, 256, 0, stream>>>(W1, b1, acc, positive, outv);
}

// Round 10
// 670.527 us; speedup vs baseline: 2.0575x; 2.0575x over previous
//
#include <hip/hip_runtime.h>
#include <math.h>

#define TPB 256
#define LRATE 0.005f

// Bucketed CSR build parameters
#define LOG_NPB 11
#define NPB (1 << LOG_NPB)   // 2048 nodes per bucket
#define CAP 24576            // max edges/bucket (mean 20480 @ avg deg 10; +28 sigma)
#define CHUNK 4096           // edges per partition block
#define CPT (CHUNK / TPB)    // 16 edges per thread

#define GATHER_BLOCKS 2048   // grid-stride groups for the epilogue kernel

// ---------------------------------------------------------------------------
// fp8 e4m3fn helpers (OCP). hp values |v| ~ O(10) << 448.
#if __has_builtin(__builtin_amdgcn_cvt_f32_fp8) && __has_builtin(__builtin_amdgcn_cvt_pk_fp8_f32)
__device__ __forceinline__ float fp8_dec(unsigned char v) {
    return __builtin_amdgcn_cvt_f32_fp8((int)v, 0);
}
__device__ __forceinline__ unsigned fp8_pk4(float a, float b, float c, float d) {
    int w = __builtin_amdgcn_cvt_pk_fp8_f32(a, b, 0, false);
    w = __builtin_amdgcn_cvt_pk_fp8_f32(c, d, w, true);
    return (unsigned)w;
}
#else
__device__ __forceinline__ unsigned char fp8_enc1(float f) {
    unsigned u = __float_as_uint(f);
    unsigned s = (u >> 24) & 0x80u;
    u &= 0x7FFFFFFFu;
    if (u >= 0x43E00000u) return (unsigned char)(s | 0x7E);
    if (u < 0x3C800000u) {
        float a = __uint_as_float(u);
        int m = (int)rintf(a * 512.f);
        return (unsigned char)(s | (unsigned)m);
    }
    unsigned mant = u & 0x7FFFFFu;
    unsigned rest = mant & 0xFFFFFu;
    unsigned keep = u >> 20;
    keep += (rest > 0x80000u || (rest == 0x80000u && (keep & 1u))) ? 1u : 0u;
    int eb = (int)(keep >> 3) - 127 + 7;
    return (unsigned char)(s | (unsigned)((eb << 3) | (int)(keep & 7u)));
}
__device__ __forceinline__ float fp8_dec(unsigned char v) {
    unsigned s = ((unsigned)(v & 0x80u)) << 24;
    unsigned e = (v >> 3) & 0xFu;
    unsigned m = v & 7u;
    if (e == 0) {
        float r = (float)m * 0.001953125f;
        return (v & 0x80u) ? -r : r;
    }
    return __uint_as_float(s | ((e + 120u) << 23) | (m << 20));
}
__device__ __forceinline__ unsigned fp8_pk4(float a, float b, float c, float d) {
    return (unsigned)fp8_enc1(a) | ((unsigned)fp8_enc1(b) << 8) |
           ((unsigned)fp8_enc1(c) << 16) | ((unsigned)fp8_enc1(d) << 24);
}
#endif

// bf16 helpers for the inter-phase partial buffer
__device__ __forceinline__ unsigned short bf16_rne(float f) {
    unsigned u = __float_as_uint(f);
    return (unsigned short)((u + 0x7FFFu + ((u >> 16) & 1u)) >> 16);
}
__device__ __forceinline__ float bf16_to_f32(unsigned short v) {
    return __uint_as_float(((unsigned)v) << 16);
}

// ---------------------------------------------------------------------------
// K_PART: partition edges into per-bucket record arrays (bucket = dst >> 11).
__global__ __launch_bounds__(TPB) void k_partition(const int* __restrict__ src,
                                                   const int* __restrict__ dst,
                                                   int* __restrict__ bcur,
                                                   int* __restrict__ grec,
                                                   int E, int nbuck) {
    __shared__ int hist[TPB];
    __shared__ int sc[TPB];
    __shared__ int lstart[TPB];
    __shared__ int lcur[TPB];
    __shared__ int gbase[TPB];
    __shared__ int lbuf[CHUNK];
    __shared__ unsigned char bbuf[CHUNK];

    int t = threadIdx.x;
    int chunkBase = blockIdx.x * CHUNK;
    hist[t] = 0;
    __syncthreads();

    int myb[CPT], myrec[CPT];
#pragma unroll
    for (int k = 0; k < CPT; k++) {
        int e = chunkBase + k * TPB + t;
        if (e < E) {
            int d = dst[e];
            int s = src[e];
            int b = d >> LOG_NPB;
            myb[k] = b;
            myrec[k] = (s << LOG_NPB) | (d & (NPB - 1));
            atomicAdd(&hist[b], 1);
        } else myb[k] = -1;
    }
    __syncthreads();

    int c = hist[t];
    sc[t] = c;
    __syncthreads();
#pragma unroll
    for (int off = 1; off < TPB; off <<= 1) {
        int add = (t >= off) ? sc[t - off] : 0;
        __syncthreads();
        sc[t] += add;
        __syncthreads();
    }
    int excl = sc[t] - c;
    lstart[t] = excl;
    lcur[t] = excl;
    if (t < nbuck && c > 0) gbase[t] = atomicAdd(&bcur[t * 16], c);
    __syncthreads();

#pragma unroll
    for (int k = 0; k < CPT; k++) {
        if (myb[k] >= 0) {
            int p = atomicAdd(&lcur[myb[k]], 1);
            lbuf[p] = myrec[k];
            bbuf[p] = (unsigned char)myb[k];
        }
    }
    __syncthreads();

    int total = E - chunkBase; if (total > CHUNK) total = CHUNK;
    for (int p = t; p < total; p += TPB) {
        int b = bbuf[p];
        int pos = gbase[b] + (p - lstart[b]);
        if (pos < CAP) grec[(size_t)b * CAP + pos] = lbuf[p];
    }
}

// K_BUILD: one block per bucket — LDS histograms (total + low-src-half), scan,
// split adjacency scatter (low srcs first), coalesced writeout.
// Emits rowptr/rowmid/rowend/dinv. LDS ~137 KB -> 1 block/CU.
__global__ __launch_bounds__(TPB) void k_build(const int* __restrict__ bcur,
                                               const int* __restrict__ grec,
                                               int* __restrict__ adj,
                                               int* __restrict__ rowptr,
                                               int* __restrict__ rowmid,
                                               int* __restrict__ rowend,
                                               float* __restrict__ dinv,
                                               int N, int half) {
    __shared__ int deg[NPB];
    __shared__ int dlo[NPB];
    __shared__ int lrow[NPB];
    __shared__ int clo[NPB];
    __shared__ int chi[NPB];
    __shared__ int sscan[TPB];
    __shared__ int adjL[CAP];

    int t = threadIdx.x;
    int b = blockIdx.x;
    int cnt = bcur[b * 16]; if (cnt > CAP) cnt = CAP;
    const int nodeBase = b << LOG_NPB;
    const size_t recBase = (size_t)b * CAP;

    for (int i = t; i < NPB; i += TPB) { deg[i] = 0; dlo[i] = 0; }
    __syncthreads();
    for (int i = t; i < cnt; i += TPB) {
        int r = grec[recBase + i];
        int node = r & (NPB - 1);
        atomicAdd(&deg[node], 1);
        if ((int)(((unsigned)r) >> LOG_NPB) < half) atomicAdd(&dlo[node], 1);
    }
    __syncthreads();

    int dv[8]; int c8 = 0;
#pragma unroll
    for (int j = 0; j < 8; j++) { dv[j] = deg[t * 8 + j]; c8 += dv[j]; }
    sscan[t] = c8;
    __syncthreads();
#pragma unroll
    for (int off = 1; off < TPB; off <<= 1) {
        int add = (t >= off) ? sscan[t - off] : 0;
        __syncthreads();
        sscan[t] += add;
        __syncthreads();
    }
    int run = sscan[t] - c8;
#pragma unroll
    for (int j = 0; j < 8; j++) { lrow[t * 8 + j] = run; run += dv[j]; }
    __syncthreads();

    for (int i = t; i < NPB; i += TPB) {
        int node = nodeBase + i;
        if (node < N) {
            int rp = (int)recBase + lrow[i];
            rowptr[node] = rp;
            rowmid[node] = rp + dlo[i];
            rowend[node] = rp + deg[i];
            dinv[node] = rsqrtf((float)(deg[i] + 1));
        }
        clo[i] = lrow[i];
        chi[i] = lrow[i] + dlo[i];
    }
    __syncthreads();

    for (int i = t; i < cnt; i += TPB) {
        int r = grec[recBase + i];
        int node = r & (NPB - 1);
        int srcid = (int)(((unsigned)r) >> LOG_NPB);
        int p = (srcid < half) ? atomicAdd(&clo[node], 1) : atomicAdd(&chi[node], 1);
        adjL[p] = srcid;
    }
    __syncthreads();
    for (int i = t; i < cnt; i += TPB) adj[recBase + i] = adjL[i];
}

// ---------------------------------------------------------------------------
// K3: hp = fp8_e4m3( dinv * (x @ W.T) ) — 16B rows. fp32 compute.
__global__ __launch_bounds__(TPB) void k_h(const float* __restrict__ xc,
                                           const float* __restrict__ W,
                                           const float* __restrict__ dinv,
                                           unsigned* __restrict__ hp, int n) {
    __shared__ float sW[256];
    if (threadIdx.x < 256) sW[threadIdx.x] = W[threadIdx.x];
    __syncthreads();
    int i = blockIdx.x * blockDim.x + threadIdx.x;
    int stride = gridDim.x * blockDim.x;
    for (; i < n; i += stride) {
        float x[16];
        const float4* xr = (const float4*)(xc + (size_t)i * 16);
#pragma unroll
        for (int q = 0; q < 4; q++) {
            float4 v = xr[q];
            x[4*q+0] = v.x; x[4*q+1] = v.y; x[4*q+2] = v.z; x[4*q+3] = v.w;
        }
        float di = dinv[i];
        float hv[16];
#pragma unroll
        for (int j = 0; j < 16; j++) {
            float s = 0.f;
#pragma unroll
            for (int k = 0; k < 16; k++) s = fmaf(x[k], sW[j*16 + k], s);
            hv[j] = di * s;
        }
        uint4 w;
        w.x = fp8_pk4(hv[0],  hv[1],  hv[2],  hv[3]);
        w.y = fp8_pk4(hv[4],  hv[5],  hv[6],  hv[7]);
        w.z = fp8_pk4(hv[8],  hv[9],  hv[10], hv[11]);
        w.w = fp8_pk4(hv[12], hv[13], hv[14], hv[15]);
        ((uint4*)hp)[i] = w;
    }
}

// K4a (phase 1): self term + low-src-half gather. hp-low (3.8 MB) is
// L2-resident per XCD during this kernel; writes bf16 row partials.
// Kernel boundary = the grid barrier round 9's spin couldn't provide.
__global__ __launch_bounds__(TPB) void k_gather1(const int* __restrict__ rowptr,
                                                 const int* __restrict__ rowmid,
                                                 const unsigned char* __restrict__ hp,
                                                 const int* __restrict__ adj,
                                                 unsigned short* __restrict__ pp,
                                                 int n) {
    int t = blockIdx.x * blockDim.x + threadIdx.x;
    int g = t >> 4;
    int j = t & 15;
    if (g >= n) return;
    int e = rowptr[g];
    int em = rowmid[g];
    float acc = fp8_dec(hp[(size_t)g * 16 + j]);   // self-loop term
    for (; e + 3 < em; e += 4) {
        int s0 = adj[e];
        int s1 = adj[e + 1];
        int s2 = adj[e + 2];
        int s3 = adj[e + 3];
        acc += (fp8_dec(hp[(size_t)s0 * 16 + j]) + fp8_dec(hp[(size_t)s1 * 16 + j]))
             + (fp8_dec(hp[(size_t)s2 * 16 + j]) + fp8_dec(hp[(size_t)s3 * 16 + j]));
    }
    for (; e < em; e++) acc += fp8_dec(hp[(size_t)adj[e] * 16 + j]);
    pp[(size_t)g * 16 + j] = bf16_rne(acc);
}

// K4b (phase 2): high-src-half gather (hp-high L2-resident) + fused
// ReLU/z/dW/db epilogue (round-6 structure). wz=0 skips the dead z write
// on the last layer.
__global__ __launch_bounds__(TPB) void k_gather2(const int* __restrict__ rowmid,
                                                 const int* __restrict__ rowend,
                                                 const float* __restrict__ dinv,
                                                 const unsigned char* __restrict__ hp,
                                                 const float* __restrict__ b,
                                                 const float* __restrict__ xc,
                                                 float* __restrict__ z,
                                                 float* __restrict__ partial,
                                                 const int* __restrict__ adj,
                                                 const unsigned short* __restrict__ pp,
                                                 int nb, int n, int wz) {
    __shared__ float red[256][17];
    int t = threadIdx.x;
    int j = t & 15;
    int g0 = blockIdx.x * 16 + (t >> 4);
    int ngroups = gridDim.x * 16;
    float bj = b[j];

    float accW[16];
#pragma unroll
    for (int k = 0; k < 16; k++) accW[k] = 0.f;
    float accB = 0.f;

    for (int g = g0; g < n; g += ngroups) {
        int e = rowmid[g];
        int ee = rowend[g];
        float acc = bf16_to_f32(pp[(size_t)g * 16 + j]);   // phase-1 partial
        for (; e + 3 < ee; e += 4) {
            int s0 = adj[e];
            int s1 = adj[e + 1];
            int s2 = adj[e + 2];
            int s3 = adj[e + 3];
            acc += (fp8_dec(hp[(size_t)s0 * 16 + j]) + fp8_dec(hp[(size_t)s1 * 16 + j]))
                 + (fp8_dec(hp[(size_t)s2 * 16 + j]) + fp8_dec(hp[(size_t)s3 * 16 + j]));
        }
        for (; e < ee; e++) acc += fp8_dec(hp[(size_t)adj[e] * 16 + j]);

        float zj = fmaxf(fmaf(dinv[g], acc, bj), 0.f);
        if (wz) z[(size_t)g * 16 + j] = zj;
        float wdj = 4.f * zj * zj;
        accB += wdj;
        const float4* xrow = (const float4*)(xc + (size_t)g * 16);
        float4 x0 = xrow[0], x1 = xrow[1], x2 = xrow[2], x3 = xrow[3];
        accW[0]  = fmaf(x0.x, wdj, accW[0]);  accW[1]  = fmaf(x0.y, wdj, accW[1]);
        accW[2]  = fmaf(x0.z, wdj, accW[2]);  accW[3]  = fmaf(x0.w, wdj, accW[3]);
        accW[4]  = fmaf(x1.x, wdj, accW[4]);  accW[5]  = fmaf(x1.y, wdj, accW[5]);
        accW[6]  = fmaf(x1.z, wdj, accW[6]);  accW[7]  = fmaf(x1.w, wdj, accW[7]);
        accW[8]  = fmaf(x2.x, wdj, accW[8]);  accW[9]  = fmaf(x2.y, wdj, accW[9]);
        accW[10] = fmaf(x2.z, wdj, accW[10]); accW[11] = fmaf(x2.w, wdj, accW[11]);
        accW[12] = fmaf(x3.x, wdj, accW[12]); accW[13] = fmaf(x3.y, wdj, accW[13]);
        accW[14] = fmaf(x3.z, wdj, accW[14]); accW[15] = fmaf(x3.w, wdj, accW[15]);
    }

    // Block reduction: red[t][k] = accW[k] (thread t = group g, col j), then
    // dW[k][j] = sum_g red[g*16+j][k]; db[j] = sum_g red[g*16+j][16].
#pragma unroll
    for (int k = 0; k < 16; k++) red[t][k] = accW[k];
    red[t][16] = accB;
    __syncthreads();
    int kk = t >> 4;
    int jj = t & 15;
    float s = 0.f;
#pragma unroll
    for (int g = 0; g < 16; g++) s += red[g * 16 + jj][kk];
    partial[(size_t)(kk * 16 + jj) * nb + blockIdx.x] = s;
    if (t < 16) {
        float sb = 0.f;
#pragma unroll
        for (int g = 0; g < 16; g++) sb += red[g * 16 + t][16];
        partial[(size_t)(256 + t) * nb + blockIdx.x] = sb;
    }
}

// K5b: one 64-lane wave per (layer,elem): coalesced sum over nb partials.
__global__ __launch_bounds__(TPB) void k_reduce(const float* __restrict__ partial,
                                                float* __restrict__ acc,
                                                int nb, int total) {
    int wid = (blockIdx.x * blockDim.x + threadIdx.x) >> 6;
    int lane = threadIdx.x & 63;
    if (wid >= total) return;
    const float* p = partial + (size_t)wid * nb;
    float s = 0.f;
    for (int b = lane; b < nb; b += 64) s += p[b];
#pragma unroll
    for (int off = 32; off > 0; off >>= 1) s += __shfl_down(s, off, 64);
    if (lane == 0) acc[wid] = s;
}

// ---------------------------------------------------------------------------
__device__ __forceinline__ float local_loss_f(float g, int positive) {
    const float t = 0.0f;
    if (positive) {
        if (g > t + 10.f) return 0.f;
        if (g < t - 10.f) return t - g;
        return log1pf(expf(t - g));
    } else {
        if (g > t + 10.f) return t + g;
        if (g < t - 10.f) return 0.f;
        return log1pf(expf(g + t));
    }
}

__global__ void k_final(const float* __restrict__ W1, const float* __restrict__ b1,
                        const float* __restrict__ acc, const int* __restrict__ positive,
                        float* __restrict__ outv) {
    int t = threadIdx.x;
    if (t < 256) {
        int jj = t >> 4, kk = t & 15;   // Wc[jj][kk] -= LR * dW[kk][jj]
        float s = 0.f;
#pragma unroll
        for (int l = 0; l < 3; l++) s += acc[l * 272 + kk * 16 + jj];
        outv[1 + t] = W1[t] - LRATE * s;
    }
    if (t < 16) {
        float s = 0.f;
#pragma unroll
        for (int l = 0; l < 3; l++) s += acc[l * 272 + 256 + t];
        outv[257 + t] = b1[t] - LRATE * s;
    }
    if (t == 0) {
        int pos = positive[0];
        float agg = 0.f;
#pragma unroll
        for (int l = 0; l < 3; l++) {
            float g = 0.f;
#pragma unroll
            for (int jj = 0; jj < 16; jj++) g += acc[l * 272 + 256 + jj];
            g *= (1.0f / 64.0f);
            agg += local_loss_f(g, pos);
        }
        outv[0] = agg;
    }
}

extern "C" void kernel_launch(void* const* d_in, const int* in_sizes, int n_in,
                              void* d_out, int out_size, void* d_ws, size_t ws_size,
                              hipStream_t stream) {
    const float* x  = (const float*)d_in[0];
    const int*   ei = (const int*)d_in[1];
    const float* W1 = (const float*)d_in[2];
    const float* b1 = (const float*)d_in[3];
    const float* W2 = (const float*)d_in[4];
    const float* b2 = (const float*)d_in[5];
    const float* W3 = (const float*)d_in[6];
    const float* b3 = (const float*)d_in[7];
    const int* positive = (const int*)d_in[8];
    float* outv = (float*)d_out;

    const int N = in_sizes[0] / 16;
    const int E = in_sizes[1] / 2;
    const int NB = GATHER_BLOCKS;
    const int nbuck = (N + NPB - 1) >> LOG_NPB;

    char* ws = (char*)d_ws;
    size_t off = 0;
    auto carve = [&](size_t bytes) -> void* {
        void* p = ws + off;
        off = (off + bytes + 255) & ~(size_t)255;
        return p;
    };
    int*   bcur   = (int*)  carve((size_t)nbuck * 16 * 4);
    int*   adj    = (int*)  carve((size_t)nbuck * CAP * 4);   // 24 MB
    int*   rowptr = (int*)  carve((size_t)N * 4);
    int*   rowmid = (int*)  carve((size_t)N * 4);
    int*   rowend = (int*)  carve((size_t)N * 4);
    float* dinv   = (float*)carve((size_t)N * 4);
    float* acc    = (float*)carve(3 * 272 * 4);
    float* part   = (float*)carve((size_t)3 * 272 * NB * 4);
    unsigned* hp  = (unsigned*)carve((size_t)N * 16);         // fp8 rows, 8 MB
    unsigned short* pp = (unsigned short*)carve((size_t)N * 32); // bf16 partials, 16 MB
    float* P1     = (float*)carve((size_t)N * 64);
    float* P2     = (float*)carve((size_t)N * 64);
    int*   grec   = (int*)P2;   // dead after k_build; P2 first written layer 2

    (void)hipMemsetAsync(bcur, 0, (size_t)nbuck * 16 * 4, stream);

    const int* src = ei;
    const int* dst = ei + E;

    int partBlocks = (E + CHUNK - 1) / CHUNK;
    k_partition<<<partBlocks, TPB, 0, stream>>>(src, dst, bcur, grec, E, nbuck);
    k_build<<<nbuck, TPB, 0, stream>>>(bcur, grec, adj, rowptr, rowmid, rowend,
                                       dinv, N, N / 2);

    const float* bss[3] = {b1, b2, b3};
    const float* Ws[3] = {W1, W2, W3};
    float* outs[3] = {P1, P2, P1};

    int nodeBlocks = (N + TPB - 1) / TPB;
    int g1Blocks = (N * 16 + TPB - 1) / TPB;

    const float* xc = x;
    for (int l = 0; l < 3; l++) {
        k_h<<<nodeBlocks, TPB, 0, stream>>>(xc, Ws[l], dinv, hp, N);
        k_gather1<<<g1Blocks, TPB, 0, stream>>>(rowptr, rowmid,
                                                (const unsigned char*)hp, adj, pp, N);
        k_gather2<<<NB, TPB, 0, stream>>>(rowmid, rowend, dinv,
                                          (const unsigned char*)hp, bss[l],
                                          xc, outs[l],
                                          part + (size_t)l * 272 * NB,
                                          adj, pp, NB, N, (l < 2) ? 1 : 0);
        xc = outs[l];
    }
    int totalElems = 3 * 272;
    k_reduce<<<(totalElems * 64 + TPB - 1) / TPB, TPB, 0, stream>>>(part, acc, NB, totalElems);
    k_final<<<1, 256, 0, stream>>>(W1, b1, acc, positive, outv);
}